// Round 7
// baseline (259.423 us; speedup 1.0000x reference)
//
#include <hip/hip_runtime.h>
#include <hip/hip_bf16.h>
#include <hip/hip_fp16.h>
#include <cmath>

constexpr int N_ = 2;
constexpr int L_ = 2048;
constexpr int H_ = 16;
constexpr int E_ = 1024;
constexpr int ROWS_ = N_ * L_ * H_;   // 65536 token-head rows
constexpr float KSCALE = 0.04508422002778010648f;   // log2(e)/32, folded into k

typedef __attribute__((ext_vector_type(8))) short bf16x8;
typedef __attribute__((ext_vector_type(4))) float f32x4;
typedef unsigned short ushort_t;
#define MFMA16(a, b, c) __builtin_amdgcn_mfma_f32_16x16x32_bf16(a, b, c, 0, 0, 0)

__device__ __forceinline__ unsigned short f2bf(float x) {
    union { float f; unsigned u; } v; v.f = x;
    return (unsigned short)((v.u + 0x7fffu + ((v.u >> 16) & 1u)) >> 16);   // RNE
}
// HW-packed bf16 pair (v_cvt_pk_bf16_f32 on gfx950)
__device__ __forceinline__ unsigned pack2(float a, float b) {
    __hip_bfloat162 t = __float22bfloat162_rn(make_float2(a, b));
    union { __hip_bfloat162 h; unsigned u; } v; v.h = t;
    return v.u;
}
__device__ __forceinline__ ushort_t f2h(float x) {
    __half h = __float2half(x);
    union { __half h; ushort_t u; } v; v.h = h;
    return v.u;
}

// ---------------------------------------------------------------------------
// Kernel 1: per-head projections, bf16 MFMA (R6-verified).
// Emits q row-major [n][l][h][d]; k row-major PRE-SCALED by log2(e)/32;
// v TRANSPOSED [n][h][d][l].
// ---------------------------------------------------------------------------
__global__ __launch_bounds__(256) void proj_kernel(
    const float* __restrict__ keys, const float* __restrict__ queries,
    const float* __restrict__ Wk, const float* __restrict__ Wq, const float* __restrict__ Wv,
    ushort_t* __restrict__ qo, ushort_t* __restrict__ ko, ushort_t* __restrict__ vto)
{
    constexpr int P = 72;
    __shared__ __align__(16) ushort_t Xq[64 * P];
    __shared__ __align__(16) ushort_t Xk[64 * P];
    __shared__ __align__(16) ushort_t Wqs[64 * P];
    __shared__ __align__(16) ushort_t Wks[64 * P];
    __shared__ __align__(16) ushort_t Wvs[64 * P];
    const int tid = threadIdx.x;
    const int lt = blockIdx.x & 31;
    const int h  = (blockIdx.x >> 5) & 15;
    const int n  = blockIdx.x >> 9;
    const int r0 = tid >> 4, c4 = (tid & 15) * 4;

#pragma unroll
    for (int j = 0; j < 4; ++j) {
        const int r = r0 + 16 * j;
        const size_t xoff = (size_t)(n * L_ + lt * 64 + r) * E_ + h * 64 + c4;
        const float4 xq = *(const float4*)&queries[xoff];
        const float4 xk = *(const float4*)&keys[xoff];
        const float4 wq = *(const float4*)&Wq[r * 64 + c4];
        const float4 wk = *(const float4*)&Wk[r * 64 + c4];
        const float4 wv = *(const float4*)&Wv[r * 64 + c4];
        *(uint2*)&Xq[r * P + c4]  = make_uint2(pack2(xq.x, xq.y), pack2(xq.z, xq.w));
        *(uint2*)&Xk[r * P + c4]  = make_uint2(pack2(xk.x, xk.y), pack2(xk.z, xk.w));
        *(uint2*)&Wqs[r * P + c4] = make_uint2(pack2(wq.x, wq.y), pack2(wq.z, wq.w));
        *(uint2*)&Wks[r * P + c4] = make_uint2(pack2(wk.x, wk.y), pack2(wk.z, wk.w));
        *(uint2*)&Wvs[r * P + c4] = make_uint2(pack2(wv.x, wv.y), pack2(wv.z, wv.w));
    }
    __syncthreads();

    const int wave = tid >> 6, lane = tid & 63;
    const int quad = lane >> 4, l16 = lane & 15;
    const int arow = (wave * 16 + l16) * P;
    const f32x4 zero = (f32x4){0.f, 0.f, 0.f, 0.f};

    bf16x8 a0 = *(const bf16x8*)&Xq[arow + quad * 8];
    bf16x8 a1 = *(const bf16x8*)&Xq[arow + 32 + quad * 8];
    bf16x8 c0 = *(const bf16x8*)&Xk[arow + quad * 8];
    bf16x8 c1 = *(const bf16x8*)&Xk[arow + 32 + quad * 8];
    f32x4 qf[4], kf[4];
#pragma unroll
    for (int nt = 0; nt < 4; ++nt) {
        const int brow = (nt * 16 + l16) * P;
        f32x4 acc = MFMA16(a0, *(const bf16x8*)&Wqs[brow + quad * 8], zero);
        qf[nt] = MFMA16(a1, *(const bf16x8*)&Wqs[brow + 32 + quad * 8], acc);
        acc = MFMA16(c0, *(const bf16x8*)&Wks[brow + quad * 8], zero);
        kf[nt] = MFMA16(c1, *(const bf16x8*)&Wks[brow + 32 + quad * 8], acc);
    }
    __syncthreads();

    const int crow = wave * 16 + quad * 4;
#pragma unroll
    for (int nt = 0; nt < 4; ++nt)
#pragma unroll
        for (int reg = 0; reg < 4; ++reg) {
            Xq[(crow + reg) * P + nt * 16 + l16]  = f2bf(qf[nt][reg]);
            Wqs[(crow + reg) * P + nt * 16 + l16] = f2bf(kf[nt][reg] * KSCALE);
        }
    asm volatile("s_waitcnt lgkmcnt(0)" ::: "memory");

    bf16x8 va0 = *(const bf16x8*)&Xq[arow + quad * 8];
    bf16x8 va1 = *(const bf16x8*)&Xq[arow + 32 + quad * 8];
    f32x4 vf[4];
#pragma unroll
    for (int nt = 0; nt < 4; ++nt) {
        const int brow = (nt * 16 + l16) * P;
        f32x4 acc = MFMA16(va0, *(const bf16x8*)&Wvs[brow + quad * 8], zero);
        vf[nt] = MFMA16(va1, *(const bf16x8*)&Wvs[brow + 32 + quad * 8], acc);
    }
#pragma unroll
    for (int nt = 0; nt < 4; ++nt)
#pragma unroll
        for (int reg = 0; reg < 4; ++reg)
            Xk[(nt * 16 + l16) * P + crow + reg] = f2bf(vf[nt][reg]);
    __syncthreads();

#pragma unroll
    for (int j = 0; j < 4; ++j) {
        const int r = r0 + 16 * j;
        const size_t qkoff = (size_t)(n * L_ + lt * 64 + r) * E_ + h * 64 + c4;
        *(uint2*)&qo[qkoff] = *(const uint2*)&Xq[r * P + c4];
        *(uint2*)&ko[qkoff] = *(const uint2*)&Wqs[r * P + c4];
        const size_t vtoff = ((size_t)(n * H_ + h) * 64 + r) * L_ + lt * 64 + c4;
        *(uint2*)&vto[vtoff] = *(const uint2*)&Xk[r * P + c4];
    }
}

// ---------------------------------------------------------------------------
// Kernel 2: MFMA flash attention, K-SPLIT x2. Grid 1024 (4 blocks/CU, 16
// waves/CU). Block = 4 waves x 32 q-rows = 128 q-rows, 16 K-tiles (half the
// key range). Shift-free softmax => partials combine by ADDITION: each block
// emits unnormalized O (fp16) and l (fp32); combine kernel divides.
// Single K/V buffer, 2 barriers/tile (R5 structure). Mask via inline int4
// load + select into MFMA C-init (0/-1e9). XCD swizzle for K/V L2 locality.
// ---------------------------------------------------------------------------
__global__ __launch_bounds__(256, 4) void attn_kernel(
    const ushort_t* __restrict__ q, const ushort_t* __restrict__ k,
    const ushort_t* __restrict__ vt, const int* __restrict__ mask,
    ushort_t* __restrict__ Oa, ushort_t* __restrict__ Ob,
    float* __restrict__ la, float* __restrict__ lb)
{
    constexpr int P = 72;
    __shared__ __align__(16) ushort_t Ks[64 * P];
    __shared__ __align__(16) ushort_t VTs[64 * P];
    __shared__ __align__(16) ushort_t Ps[128 * P];

    // decode: xcd = g&7 serves heads [4*xcd, 4*xcd+4)
    const int g = blockIdx.x;
    const int xcd = g & 7, j0 = g >> 3;          // j0 in [0,128)
    const int nh = xcd * 4 + (j0 & 3);
    const int rest = j0 >> 2;                    // [0,32)
    const int qt = rest & 15;                    // 128-row q tile
    const int half = rest >> 4;                  // K half
    const int n = nh >> 4, h = nh & 15;
    const int t0 = half * 16;

    ushort_t* __restrict__ Op = half ? Ob : Oa;
    float*    __restrict__ lp = half ? lb : la;

    const int tid = threadIdx.x;
    const int wave = tid >> 6, lane = tid & 63;
    const int l16 = lane & 15, quad = lane >> 4;
    const int r0 = tid >> 4, c4 = (tid & 15) * 4;

    const ushort_t* kh = k  + (size_t)n * L_ * E_ + h * 64;      // + key*E_ + d
    const ushort_t* vh = vt + (size_t)(n * H_ + h) * 64 * L_;    // + d*L_ + key
    const int*      mh = mask + n * L_;
    const size_t qrow0 = (size_t)n * L_ + qt * 128 + wave * 32;

    // hoisted Q B-frags [strip][chain] (t-invariant)
    bf16x8 qb[2][2];
#pragma unroll
    for (int s = 0; s < 2; ++s)
#pragma unroll
        for (int c = 0; c < 2; ++c)
            qb[s][c] = *(const bf16x8*)&q[(qrow0 + s * 16 + l16) * E_ + h * 64 + c * 32 + quad * 8];

    // tile-t0 staging prefetch + mask C-init
    uint2 kr[4], vr[4];
#pragma unroll
    for (int j = 0; j < 4; ++j) {
        const int r = r0 + 16 * j;
        kr[j] = *(const uint2*)&kh[(size_t)(t0 * 64 + r) * E_ + c4];
        vr[j] = *(const uint2*)&vh[(size_t)r * L_ + t0 * 64 + c4];
    }
    f32x4 mf[4];
#pragma unroll
    for (int mk = 0; mk < 4; ++mk) {
        const int4 mi = *(const int4*)&mh[t0 * 64 + mk * 16 + quad * 4];
        mf[mk] = (f32x4){mi.x ? 0.f : -1e9f, mi.y ? 0.f : -1e9f,
                         mi.z ? 0.f : -1e9f, mi.w ? 0.f : -1e9f};
    }

    float lacc[2] = {0.f, 0.f};
    f32x4 O[2][4];
#pragma unroll
    for (int s = 0; s < 2; ++s)
#pragma unroll
        for (int dt = 0; dt < 4; ++dt) O[s][dt] = (f32x4){0.f, 0.f, 0.f, 0.f};

    for (int t = t0; t < t0 + 16; ++t) {
        // commit staged tile
#pragma unroll
        for (int j = 0; j < 4; ++j) {
            const int r = r0 + 16 * j;
            *(uint2*)&Ks[r * P + c4]  = kr[j];
            *(uint2*)&VTs[r * P + c4] = vr[j];
        }
        __syncthreads();

        // prefetch t+1 (in flight during compute)
        const int tn = (t < t0 + 15) ? t + 1 : t;
#pragma unroll
        for (int j = 0; j < 4; ++j) {
            const int r = r0 + 16 * j;
            kr[j] = *(const uint2*)&kh[(size_t)(tn * 64 + r) * E_ + c4];
            vr[j] = *(const uint2*)&vh[(size_t)r * L_ + tn * 64 + c4];
        }
        f32x4 mfn[4];
#pragma unroll
        for (int mk = 0; mk < 4; ++mk) {
            const int4 mi = *(const int4*)&mh[tn * 64 + mk * 16 + quad * 4];
            mfn[mk] = (f32x4){mi.x ? 0.f : -1e9f, mi.y ? 0.f : -1e9f,
                              mi.z ? 0.f : -1e9f, mi.w ? 0.f : -1e9f};
        }

        // K A-frags (strip-invariant)
        bf16x8 kA[4][2];
#pragma unroll
        for (int mk = 0; mk < 4; ++mk)
#pragma unroll
            for (int c = 0; c < 2; ++c)
                kA[mk][c] = *(const bf16x8*)&Ks[(mk * 16 + l16) * P + c * 32 + quad * 8];

        // S^T = K'*Q^T + mask_init : C[key=16mk+quad*4+reg][q=l16]
        f32x4 sA[2][4];
#pragma unroll
        for (int s = 0; s < 2; ++s)
#pragma unroll
            for (int mk = 0; mk < 4; ++mk) {
                f32x4 acc = mf[mk];
                acc = MFMA16(kA[mk][0], qb[s][0], acc);
                sA[s][mk] = MFMA16(kA[mk][1], qb[s][1], acc);
            }

        // p = exp2(s) (K pre-scaled); packed b64 writes into P[q][key]
#pragma unroll
        for (int s = 0; s < 2; ++s)
#pragma unroll
            for (int mk = 0; mk < 4; ++mk) {
                const float p0 = __builtin_amdgcn_exp2f(sA[s][mk][0]);
                const float p1 = __builtin_amdgcn_exp2f(sA[s][mk][1]);
                const float p2 = __builtin_amdgcn_exp2f(sA[s][mk][2]);
                const float p3 = __builtin_amdgcn_exp2f(sA[s][mk][3]);
                lacc[s] += (p0 + p1) + (p2 + p3);
                *(uint2*)&Ps[(wave * 32 + s * 16 + l16) * P + mk * 16 + quad * 4] =
                    make_uint2(pack2(p0, p1), pack2(p2, p3));
            }
        asm volatile("s_waitcnt lgkmcnt(0)" ::: "memory");   // wave-private P

        // O += P*V ; V B-frags strip-invariant
        bf16x8 vB[4][2];
#pragma unroll
        for (int dt = 0; dt < 4; ++dt)
#pragma unroll
            for (int c = 0; c < 2; ++c)
                vB[dt][c] = *(const bf16x8*)&VTs[(dt * 16 + l16) * P + c * 32 + quad * 8];
        bf16x8 pa[2][2];
#pragma unroll
        for (int s = 0; s < 2; ++s)
#pragma unroll
            for (int c = 0; c < 2; ++c)
                pa[s][c] = *(const bf16x8*)&Ps[(wave * 32 + s * 16 + l16) * P + c * 32 + quad * 8];
#pragma unroll
        for (int s = 0; s < 2; ++s)
#pragma unroll
            for (int dt = 0; dt < 4; ++dt) {
                O[s][dt] = MFMA16(pa[s][0], vB[dt][0], O[s][dt]);
                O[s][dt] = MFMA16(pa[s][1], vB[dt][1], O[s][dt]);
            }
#pragma unroll
        for (int mk = 0; mk < 4; ++mk) mf[mk] = mfn[mk];
        __syncthreads();   // protect Ks/VTs before next commit
    }

    // partial l: reduce across quads (lane's l16 = q), store fp32
#pragma unroll
    for (int s = 0; s < 2; ++s) {
        float v = lacc[s];
        v += __shfl_xor(v, 16);
        v += __shfl_xor(v, 32);
        if (quad == 0)
            lp[((size_t)(n * H_ + h)) * L_ + qt * 128 + wave * 32 + s * 16 + l16] = v;
    }
    // partial O (unnormalized, fp16)
#pragma unroll
    for (int s = 0; s < 2; ++s)
#pragma unroll
        for (int dt = 0; dt < 4; ++dt)
#pragma unroll
            for (int reg = 0; reg < 4; ++reg) {
                const size_t row = qrow0 + s * 16 + quad * 4 + reg;
                Op[row * E_ + h * 64 + dt * 16 + l16] = f2h(O[s][dt][reg]);
            }
}

// ---------------------------------------------------------------------------
// Kernel 3: combine K-split partials: abf = bf16((Oa+Ob) / (la+lb))
// ---------------------------------------------------------------------------
__global__ __launch_bounds__(256) void combine_kernel(
    const ushort_t* __restrict__ Oa, const ushort_t* __restrict__ Ob,
    const float* __restrict__ la, const float* __restrict__ lb,
    ushort_t* __restrict__ abf)
{
    const size_t i = ((size_t)blockIdx.x * 256 + threadIdx.x) * 4;
    const int row = (int)(i >> 10);            // n*L + l
    const int col = (int)(i & 1023);
    const int h = col >> 6;
    const int n = row >> 11, l = row & 2047;
    const size_t lidx = ((size_t)(n * H_ + h)) * L_ + l;
    const float inv = 1.f / (la[lidx] + lb[lidx]);
    const __half2* A2 = (const __half2*)&Oa[i];
    const __half2* B2 = (const __half2*)&Ob[i];
    const float2 a0 = __half22float2(A2[0]), a1 = __half22float2(A2[1]);
    const float2 b0 = __half22float2(B2[0]), b1 = __half22float2(B2[1]);
    *(uint2*)&abf[i] = make_uint2(
        pack2((a0.x + b0.x) * inv, (a0.y + b0.y) * inv),
        pack2((a1.x + b1.x) * inv, (a1.y + b1.y) * inv));
}

// ---------------------------------------------------------------------------
// Kernel 4: out = attn(4096x1024) @ Wo^T + bo. 128x64 tiles, 2-strip waves.
// Wo read fp32 and packed to bf16 during staging (conv kernel eliminated).
// ---------------------------------------------------------------------------
__global__ __launch_bounds__(256) void outproj_kernel(
    const ushort_t* __restrict__ attn, const float* __restrict__ Wo,
    const float* __restrict__ bo, float* __restrict__ out)
{
    constexpr int P = 72;
    __shared__ __align__(16) ushort_t As[128 * P];
    __shared__ __align__(16) ushort_t Bs[64 * P];
    const int tid = threadIdx.x;
    const int bc = (blockIdx.x & 15) * 64;
    const int br = (blockIdx.x >> 4) * 128;
    const int r0 = tid >> 4, c4 = (tid & 15) * 4;
    const int wave = tid >> 6, lane = tid & 63;
    const int quad = lane >> 4, l16 = lane & 15;

    uint2 ar[8]; float4 wr[4];
#pragma unroll
    for (int j = 0; j < 8; ++j)
        ar[j] = *(const uint2*)&attn[(size_t)(br + r0 + 16 * j) * E_ + c4];
#pragma unroll
    for (int j = 0; j < 4; ++j)
        wr[j] = *(const float4*)&Wo[(size_t)(bc + r0 + 16 * j) * E_ + c4];

    f32x4 acc[2][4];
#pragma unroll
    for (int s = 0; s < 2; ++s)
#pragma unroll
        for (int nt = 0; nt < 4; ++nt) acc[s][nt] = (f32x4){0.f, 0.f, 0.f, 0.f};

    for (int kt = 0; kt < 16; ++kt) {
#pragma unroll
        for (int j = 0; j < 8; ++j) *(uint2*)&As[(r0 + 16 * j) * P + c4] = ar[j];
#pragma unroll
        for (int j = 0; j < 4; ++j)
            *(uint2*)&Bs[(r0 + 16 * j) * P + c4] =
                make_uint2(pack2(wr[j].x, wr[j].y), pack2(wr[j].z, wr[j].w));
        __syncthreads();
        const int knext = ((kt < 15) ? (kt + 1) : kt) * 64;
#pragma unroll
        for (int j = 0; j < 8; ++j)
            ar[j] = *(const uint2*)&attn[(size_t)(br + r0 + 16 * j) * E_ + knext + c4];
#pragma unroll
        for (int j = 0; j < 4; ++j)
            wr[j] = *(const float4*)&Wo[(size_t)(bc + r0 + 16 * j) * E_ + knext + c4];

        bf16x8 aw[2][2], bw[4][2];
#pragma unroll
        for (int s = 0; s < 2; ++s)
#pragma unroll
            for (int c = 0; c < 2; ++c)
                aw[s][c] = *(const bf16x8*)&As[(wave * 32 + s * 16 + l16) * P + c * 32 + quad * 8];
#pragma unroll
        for (int nt = 0; nt < 4; ++nt)
#pragma unroll
            for (int c = 0; c < 2; ++c)
                bw[nt][c] = *(const bf16x8*)&Bs[(nt * 16 + l16) * P + c * 32 + quad * 8];
#pragma unroll
        for (int s = 0; s < 2; ++s)
#pragma unroll
            for (int nt = 0; nt < 4; ++nt) {
                acc[s][nt] = MFMA16(aw[s][0], bw[nt][0], acc[s][nt]);
                acc[s][nt] = MFMA16(aw[s][1], bw[nt][1], acc[s][nt]);
            }
        __syncthreads();
    }
#pragma unroll
    for (int s = 0; s < 2; ++s)
#pragma unroll
        for (int nt = 0; nt < 4; ++nt) {
            const float bias = bo[bc + nt * 16 + l16];
#pragma unroll
            for (int reg = 0; reg < 4; ++reg)
                out[(size_t)(br + wave * 32 + s * 16 + quad * 4 + reg) * E_ + bc + nt * 16 + l16] =
                    acc[s][nt][reg] + bias;
        }
}

// ---------------------------------------------------------------------------
extern "C" void kernel_launch(void* const* d_in, const int* in_sizes, int n_in,
                              void* d_out, int out_size, void* d_ws, size_t ws_size,
                              hipStream_t stream)
{
    const float* keys    = (const float*)d_in[0];
    const float* queries = (const float*)d_in[1];
    // d_in[2] (values) is UNUSED by the reference: v = q @ Wv.T
    const int*   mask    = (const int*)d_in[3];
    const float* Wk      = (const float*)d_in[4];
    const float* Wq      = (const float*)d_in[5];
    const float* Wv      = (const float*)d_in[6];
    const float* Wo      = (const float*)d_in[7];
    const float* bo      = (const float*)d_in[8];
    float* out = (float*)d_out;

    // workspace: q,k,vT bf16 (8 MB each), Oa/Ob fp16 (8 MB each),
    // la/lb fp32 (256 KB each), abf bf16 (8 MB)  => ~48.5 MB
    ushort_t* qbf  = (ushort_t*)d_ws;
    ushort_t* kbf  = qbf  + (size_t)ROWS_ * 64;
    ushort_t* vtbf = kbf  + (size_t)ROWS_ * 64;
    ushort_t* Oa   = vtbf + (size_t)ROWS_ * 64;
    ushort_t* Ob   = Oa   + (size_t)ROWS_ * 64;
    ushort_t* abf  = Ob   + (size_t)ROWS_ * 64;
    float*    la   = (float*)(abf + (size_t)ROWS_ * 64);
    float*    lb   = la + (size_t)N_ * H_ * L_;

    proj_kernel<<<N_ * H_ * (L_ / 64), 256, 0, stream>>>(keys, queries, Wk, Wq, Wv,
                                                         qbf, kbf, vtbf);
    attn_kernel<<<N_ * H_ * (L_ / 128) * 2, 256, 0, stream>>>(qbf, kbf, vtbf, mask,
                                                              Oa, Ob, la, lb);
    combine_kernel<<<(N_ * L_ * E_ / 4) / 256, 256, 0, stream>>>(Oa, Ob, la, lb, abf);
    outproj_kernel<<<(N_ * L_ / 128) * (E_ / 64), 256, 0, stream>>>(abf, Wo, bo, out);
}